// Round 2
// baseline (232.649 us; speedup 1.0000x reference)
//
#include <hip/hip_runtime.h>

#define BB 32
#define TT 36
#define NN 10000
#define FF 3
#define HH 10
#define RR 20
#define NQ (NN / 4)   // 2500 quads of nodes per batch

// ws layout (floats):
//   [0, BB*NN)      : time_mean (NaN where node all-NaN)
//   [+BB*RR]        : per-(b,region) sum
//   [+BB*RR]        : per-(b,region) count
//   [+1]            : global sum
//   [+1]            : global count
//   [+1]            : g1

__global__ __launch_bounds__(256) void k_time_mean(
        const float* __restrict__ seq,
        const int* __restrict__ cid,
        float* __restrict__ tm,
        float* __restrict__ rsum,
        float* __restrict__ rcnt,
        float* __restrict__ gsum,
        float* __restrict__ gcnt) {
    __shared__ float ls[RR];
    __shared__ float lc[RR];
    const int b = blockIdx.y;
    const int q = blockIdx.x * blockDim.x + threadIdx.x;  // quad index 0..2499
    if (threadIdx.x < RR) { ls[threadIdx.x] = 0.f; lc[threadIdx.x] = 0.f; }
    __syncthreads();

    float lsum = 0.f, lcnt = 0.f;  // this thread's contribution to global nanmean

    if (q < NQ) {
        // 4 nodes -> 12 consecutive floats per t -> 3 aligned float4 loads
        const float4* p = (const float4*)seq + (size_t)b * TT * NN * FF / 4 + 3 * q;
        const size_t tstride = (size_t)NN * FF / 4;  // 7500 float4s per t
        float s0 = 0.f, s1 = 0.f, s2 = 0.f, s3 = 0.f;
        int c0 = 0, c1 = 0, c2 = 0, c3 = 0;
        #pragma unroll
        for (int t = 0; t < TT; ++t) {
            float4 q0 = p[0];
            float4 q1 = p[1];
            float4 q2 = p[2];
            p += tstride;
            float v0 = q0.x, v1 = q0.w, v2 = q1.z, v3 = q2.y;
            if (v0 == v0) { s0 += v0; c0++; }
            if (v1 == v1) { s1 += v1; c1++; }
            if (v2 == v2) { s2 += v2; c2++; }
            if (v3 == v3) { s3 += v3; c3++; }
        }
        const float nanf_ = __int_as_float(0x7fc00000);
        float m0 = c0 ? s0 / (float)c0 : nanf_;
        float m1 = c1 ? s1 / (float)c1 : nanf_;
        float m2 = c2 ? s2 / (float)c2 : nanf_;
        float m3 = c3 ? s3 / (float)c3 : nanf_;
        ((float4*)tm)[(size_t)b * NQ + q] = make_float4(m0, m1, m2, m3);

        const int4 r4 = ((const int4*)cid)[q];
        if (c0) { atomicAdd(&ls[r4.x], m0); atomicAdd(&lc[r4.x], 1.f); lsum += m0; lcnt += 1.f; }
        if (c1) { atomicAdd(&ls[r4.y], m1); atomicAdd(&lc[r4.y], 1.f); lsum += m1; lcnt += 1.f; }
        if (c2) { atomicAdd(&ls[r4.z], m2); atomicAdd(&lc[r4.z], 1.f); lsum += m2; lcnt += 1.f; }
        if (c3) { atomicAdd(&ls[r4.w], m3); atomicAdd(&lc[r4.w], 1.f); lsum += m3; lcnt += 1.f; }
    }

    // wave-level reduction of global sum/count; one global atomic per wave
    for (int off = 32; off > 0; off >>= 1) {
        lsum += __shfl_down(lsum, off, 64);
        lcnt += __shfl_down(lcnt, off, 64);
    }
    if ((threadIdx.x & 63) == 0) {
        atomicAdd(gsum, lsum);
        atomicAdd(gcnt, lcnt);
    }

    __syncthreads();
    if (threadIdx.x < RR) {
        atomicAdd(&rsum[b * RR + threadIdx.x], ls[threadIdx.x]);
        atomicAdd(&rcnt[b * RR + threadIdx.x], lc[threadIdx.x]);
    }
}

// single block, 640 threads (B*R = 640 = 10 waves)
__global__ void k_regional(const float* __restrict__ rsum,
                           const float* __restrict__ rcnt,
                           const float* __restrict__ gsum,
                           const float* __restrict__ gcnt,
                           float* __restrict__ g1out,
                           float* __restrict__ out_reg) {
    const int tid = threadIdx.x;
    __shared__ float ssum[10];
    __shared__ float scnt[10];
    __shared__ float g2s;

    float val = 0.f;
    int valid = 0;
    if (tid < BB * RR) {
        float c = rcnt[tid];
        if (c > 0.f) { val = rsum[tid] / c; valid = 1; }
    }

    float wsv = valid ? val : 0.f;
    float wcv = (float)valid;
    for (int off = 32; off > 0; off >>= 1) {
        wsv += __shfl_down(wsv, off, 64);
        wcv += __shfl_down(wcv, off, 64);
    }
    const int wave = tid >> 6;
    if ((tid & 63) == 0) { ssum[wave] = wsv; scnt[wave] = wcv; }
    __syncthreads();

    if (tid == 0) {
        float s = 0.f, c = 0.f;
        #pragma unroll
        for (int i = 0; i < 10; ++i) { s += ssum[i]; c += scnt[i]; }
        g2s = s / c;
        g1out[0] = gsum[0] / gcnt[0];
    }
    __syncthreads();

    if (tid < BB * RR) {
        const int b = tid / RR, r = tid % RR;
        const float o = valid ? val : g2s;
        #pragma unroll
        for (int h = 0; h < HH; ++h)
            out_reg[(size_t)(b * HH + h) * RR + r] = o;
    }
}

__global__ __launch_bounds__(256) void k_pred(
        const float* __restrict__ tm,
        const float* __restrict__ g1p,
        float* __restrict__ out) {
    const int b = blockIdx.y;
    const int q = blockIdx.x * blockDim.x + threadIdx.x;  // quad 0..2499
    if (q >= NQ) return;
    const float g1 = g1p[0];
    float4 v = ((const float4*)tm)[(size_t)b * NQ + q];
    if (!(v.x == v.x)) v.x = g1;
    if (!(v.y == v.y)) v.y = g1;
    if (!(v.z == v.z)) v.z = g1;
    if (!(v.w == v.w)) v.w = g1;
    float4* o = (float4*)out + (size_t)b * HH * NQ + q;
    #pragma unroll
    for (int h = 0; h < HH; ++h)
        o[(size_t)h * NQ] = v;
}

extern "C" void kernel_launch(void* const* d_in, const int* in_sizes, int n_in,
                              void* d_out, int out_size, void* d_ws, size_t ws_size,
                              hipStream_t stream) {
    const float* seq = (const float*)d_in[0];
    const int*   cid = (const int*)d_in[1];
    float* out = (float*)d_out;

    float* ws   = (float*)d_ws;
    float* tm   = ws;                     // BB*NN
    float* rsum = tm + BB * NN;           // BB*RR
    float* rcnt = rsum + BB * RR;         // BB*RR
    float* gsum = rcnt + BB * RR;         // 1
    float* gcnt = gsum + 1;               // 1
    float* g1   = gcnt + 1;               // 1

    hipMemsetAsync(rsum, 0, (size_t)(2 * BB * RR + 2) * sizeof(float), stream);

    dim3 blk(256);
    dim3 grd((NQ + 255) / 256, BB);       // 10 x 32 blocks
    k_time_mean<<<grd, blk, 0, stream>>>(seq, cid, tm, rsum, rcnt, gsum, gcnt);
    k_regional<<<1, 640, 0, stream>>>(rsum, rcnt, gsum, gcnt, g1,
                                      out + (size_t)BB * HH * NN);
    k_pred<<<grd, blk, 0, stream>>>(tm, g1, out);
}